// Round 6
// baseline (462.153 us; speedup 1.0000x reference)
//
#include <hip/hip_runtime.h>
#include <hip/hip_bf16.h>
#include <stdint.h>

#define B_ 32
#define N_ 1024
#define D_ 1024

typedef __bf16 bf16x8 __attribute__((ext_vector_type(8)));
typedef float f32x16 __attribute__((ext_vector_type(16)));

static __device__ __forceinline__ unsigned short f2bf(float f) {
    union { float f; unsigned u; } v; v.f = f;
    unsigned r = v.u + 0x7fffu + ((v.u >> 16) & 1u);   // round-to-nearest-even
    return (unsigned short)(r >> 16);
}

static __device__ __forceinline__ void gld_lds16(const void* g, void* l) {
    __builtin_amdgcn_global_load_lds(
        (const __attribute__((address_space(1))) void*)g,
        (__attribute__((address_space(3))) void*)l, 16, 0, 0);
}

// ---------------------------------------------------------------------------
// K1: wave-per-row softmax stats. 4 rows/block, no __syncthreads.
// Also zeroes this block's 4 rowsum entries (fused memset).
// ---------------------------------------------------------------------------
__global__ __launch_bounds__(256) void prep_kernel(const float* __restrict__ x,
        unsigned short* __restrict__ pb, unsigned short* __restrict__ xb,
        float* __restrict__ lse, float* __restrict__ rowsum) {
    if (threadIdx.x < 4) rowsum[blockIdx.x * 4 + threadIdx.x] = 0.0f;

    int row  = blockIdx.x * 4 + (threadIdx.x >> 6);
    int lane = threadIdx.x & 63;
    const float4* xr = (const float4*)(x + (size_t)row * D_);

    float4 v[4];
    #pragma unroll
    for (int q = 0; q < 4; q++) v[q] = xr[lane + 64 * q];

    float m = -1e30f;
    #pragma unroll
    for (int q = 0; q < 4; q++)
        m = fmaxf(m, fmaxf(fmaxf(v[q].x, v[q].y), fmaxf(v[q].z, v[q].w)));
    #pragma unroll
    for (int o = 1; o < 64; o <<= 1) m = fmaxf(m, __shfl_xor(m, o, 64));

    float4 e[4];
    float s = 0.0f;
    #pragma unroll
    for (int q = 0; q < 4; q++) {
        e[q].x = __expf(v[q].x - m); e[q].y = __expf(v[q].y - m);
        e[q].z = __expf(v[q].z - m); e[q].w = __expf(v[q].w - m);
        s += e[q].x + e[q].y + e[q].z + e[q].w;
    }
    #pragma unroll
    for (int o = 1; o < 64; o <<= 1) s += __shfl_xor(s, o, 64);
    float inv = 1.0f / s;

    ushort4* pr = (ushort4*)(pb + (size_t)row * D_);
    ushort4* xw = (ushort4*)(xb + (size_t)row * D_);
    #pragma unroll
    for (int q = 0; q < 4; q++) {
        ushort4 pu, xu;
        pu.x = f2bf(e[q].x * inv); pu.y = f2bf(e[q].y * inv);
        pu.z = f2bf(e[q].z * inv); pu.w = f2bf(e[q].w * inv);
        xu.x = f2bf(v[q].x); xu.y = f2bf(v[q].y);
        xu.z = f2bf(v[q].z); xu.w = f2bf(v[q].w);
        pr[lane + 64 * q] = pu;
        xw[lane + 64 * q] = xu;
    }
    if (lane == 0) lse[row] = m + logf(s);
}

// ---------------------------------------------------------------------------
// K2/K4: batched bf16 GEMM, C[m][n] = sum_k A[m][k]*B[n][k], fused epilogues.
// Round-6: 256x128 tile, 8 waves (4Mx2N), per-wave 64x64 via 2x2x2 mfma
// 32x32x16. Reg budget <=128/wave (acc 64 AGPR + ~56 VGPR) + 72KB LDS ->
// TWO independent blocks per CU (the lockstep-stall fix: one block's MFMAs
// cover the other's barrier/DMA gaps). Triple-buffered LDS (3 x 24KB), DMA
// staged 2 tiles ahead, counted vmcnt(3) per tile (VM0 only at tail).
// Zero-conflict LDS layout (k-slot XOR swizzle on DMA source + read addr;
// each 8-lane group covers 8 distinct banksets). XCD-aware bijective swizzle.
// MODE 0 (gemm1): e = exp(acc - lse[col]) -> bf16 store + rowsum atomics.
// MODE 1 (gemm2): out = acc / rowsum[row], fp32 store.
// ---------------------------------------------------------------------------
#define VM3 asm volatile("s_waitcnt vmcnt(3)" ::: "memory")
#define VM0 asm volatile("s_waitcnt vmcnt(0)" ::: "memory")
#define VMN

#define TILE(tt, rB, wB, DOSTAGE, VM)                                           \
  {                                                                             \
    bf16x8 av[2][2], bv[2][2];                                                  \
    _Pragma("unroll") for (int kk = 0; kk < 2; ++kk) {                          \
      _Pragma("unroll") for (int i2 = 0; i2 < 2; ++i2) av[kk][i2] = lA(rB, kk, i2); \
      _Pragma("unroll") for (int j2 = 0; j2 < 2; ++j2) bv[kk][j2] = lB(rB, kk, j2); \
    }                                                                           \
    if (DOSTAGE) stage(wB, (tt) + 2);                                           \
    asm volatile("s_waitcnt lgkmcnt(0)" ::: "memory");                          \
    __builtin_amdgcn_s_setprio(1);                                              \
    _Pragma("unroll") for (int kk = 0; kk < 2; ++kk)                            \
      _Pragma("unroll") for (int i2 = 0; i2 < 2; ++i2)                          \
        _Pragma("unroll") for (int j2 = 0; j2 < 2; ++j2)                        \
          acc[i2][j2] = __builtin_amdgcn_mfma_f32_32x32x16_bf16(                \
              av[kk][i2], bv[kk][j2], acc[i2][j2], 0, 0, 0);                    \
    __builtin_amdgcn_s_setprio(0);                                              \
    VM;                                                                         \
    __builtin_amdgcn_s_barrier();                                               \
  }

template<int MODE>
__global__ __launch_bounds__(512, 4) void gemm_bt(const unsigned short* __restrict__ Ag,
        const unsigned short* __restrict__ Bg, void* __restrict__ Cg,
        const float* __restrict__ lse, float* __restrict__ rowsum) {
    const int K = 1024;

    // XCD-aware bijective swizzle: 1024 blocks = 8 XCDs x 128; each XCD gets
    // 128 consecutive logical blocks = 4 whole batches (panel L2 reuse).
    int h = blockIdx.x + 8 * blockIdx.y + 32 * blockIdx.z;   // 0..1023
    int l = (h & 7) * 128 + (h >> 3);
    int b  = l >> 5;                       // 0..31
    int m0 = ((l >> 3) & 3) * 256;         // 4 m-tiles
    int n0 = (l & 7) * 128;                // 8 n-tiles

    const unsigned short* A  = Ag + (size_t)b * N_ * K;
    const unsigned short* Bm = Bg + (size_t)b * N_ * K;

    // 3 buffers x 24KB: buf w -> A plane (16KB) at w*24576, B plane (8KB) +16384.
    extern __shared__ char lds[];

    int t = threadIdx.x;
    int wave = t >> 6, lane = t & 63;
    int wm = wave >> 1, wn = wave & 1;     // 4 x 2 wave grid, 64x64 each
    int ln31 = lane & 31, l5 = lane >> 5;

    f32x16 acc[2][2];
    #pragma unroll
    for (int i = 0; i < 2; i++)
        #pragma unroll
        for (int j = 0; j < 2; j++)
            #pragma unroll
            for (int r = 0; r < 16; r++) acc[i][j][r] = 0.0f;

    // --- staging slice: 3 x 16B loads/thread/tile (A rows rr, rr+128; B row rr)
    int rr = t >> 2, s = t & 3;            // rr 0..127, s 0..3
    int sg = s ^ ((rr >> 1) & 3);          // inverse-swizzled source k-slot
    const unsigned short* pA0 = A  + (size_t)(m0 + rr) * K + sg * 8;
    const unsigned short* pA1 = A  + (size_t)(m0 + 128 + rr) * K + sg * 8;
    const unsigned short* pB0 = Bm + (size_t)(n0 + rr) * K + sg * 8;
    int dA0 = rr * 64 + s * 16;
    int dA1 = (128 + rr) * 64 + s * 16;

    auto stage = [&](int w, int tg) {
        char* base = lds + w * 24576;
        gld_lds16(pA0 + tg * 32, base + dA0);
        gld_lds16(pA1 + tg * 32, base + dA1);
        gld_lds16(pB0 + tg * 32, base + 16384 + dA0);
    };

    // --- fragment reads: lane = (row within 32) + 32*(k-half); slot swizzle ---
    auto lA = [&](int br, int kk, int i2) {
        int row = wm * 64 + i2 * 32 + ln31;
        int sidx = kk * 2 + l5;
        return *(const bf16x8*)(lds + br * 24576 + row * 64 +
                                ((sidx ^ ((row >> 1) & 3)) * 16));
    };
    auto lB = [&](int br, int kk, int j2) {
        int row = wn * 64 + j2 * 32 + ln31;
        int sidx = kk * 2 + l5;
        return *(const bf16x8*)(lds + br * 24576 + 16384 + row * 64 +
                                ((sidx ^ ((row >> 1) & 3)) * 16));
    };

    // prologue: stage tiles 0,1; wait tile 0 (in-flight 6 -> <=3 leaves tile1).
    stage(0, 0);
    stage(1, 1);
    VM3;
    __builtin_amdgcn_s_barrier();

    for (int tp = 0; tp < 10; ++tp) {
        int t0 = tp * 3;
        TILE(t0 + 0, 0, 2, 1, VM3);
        TILE(t0 + 1, 1, 0, 1, VM3);
        TILE(t0 + 2, 2, 1, 1, VM3);
    }
    TILE(30, 0, 2, 0, VM0);
    TILE(31, 1, 0, 0, VMN);

    // epilogue: 32x32 C/D layout: col = lane&31, row = (r&3) + 8*(r>>2) + 4*(lane>>5)
    if (MODE == 0) {
        unsigned short* Co = (unsigned short*)Cg + (size_t)b * (size_t)N_ * N_;
        float lsev[2];
        #pragma unroll
        for (int j2 = 0; j2 < 2; j2++)
            lsev[j2] = lse[b * N_ + n0 + wn * 64 + j2 * 32 + ln31];
        float rsum[2][16];
        #pragma unroll
        for (int i2 = 0; i2 < 2; i2++)
            #pragma unroll
            for (int r = 0; r < 16; r++) rsum[i2][r] = 0.0f;
        #pragma unroll
        for (int i2 = 0; i2 < 2; i2++) {
            #pragma unroll
            for (int r = 0; r < 16; r++) {
                int row = m0 + wm * 64 + i2 * 32 + (r & 3) + 8 * (r >> 2) + 4 * l5;
                size_t ro = (size_t)row * N_;
                #pragma unroll
                for (int j2 = 0; j2 < 2; j2++) {
                    int col = n0 + wn * 64 + j2 * 32 + ln31;
                    float ev = __expf(acc[i2][j2][r] - lsev[j2]);  // in [e^-14, e^-1]
                    unsigned short eb = f2bf(ev);
                    union { unsigned u; float f; } bk; bk.u = ((unsigned)eb) << 16;
                    Co[ro + col] = eb;
                    rsum[i2][r] += bk.f;                           // sum the ROUNDED value
                }
            }
        }
        #pragma unroll
        for (int i2 = 0; i2 < 2; i2++) {
            #pragma unroll
            for (int r = 0; r < 16; r++) {
                float sv = rsum[i2][r];
                sv += __shfl_xor(sv, 1, 64);
                sv += __shfl_xor(sv, 2, 64);
                sv += __shfl_xor(sv, 4, 64);
                sv += __shfl_xor(sv, 8, 64);
                sv += __shfl_xor(sv, 16, 64);
                if (ln31 == 0) {
                    int row = m0 + wm * 64 + i2 * 32 + (r & 3) + 8 * (r >> 2) + 4 * l5;
                    atomicAdd(&rowsum[b * N_ + row], sv);
                }
            }
        }
    } else {
        float* Co = (float*)Cg + (size_t)b * (size_t)N_ * N_;
        #pragma unroll
        for (int i2 = 0; i2 < 2; i2++) {
            #pragma unroll
            for (int r = 0; r < 16; r++) {
                int row = m0 + wm * 64 + i2 * 32 + (r & 3) + 8 * (r >> 2) + 4 * l5;
                float inv = 1.0f / rowsum[b * N_ + row];
                size_t ro = (size_t)row * N_;
                #pragma unroll
                for (int j2 = 0; j2 < 2; j2++) {
                    int col = n0 + wn * 64 + j2 * 32 + ln31;
                    Co[ro + col] = acc[i2][j2][r] * inv;
                }
            }
        }
    }
}

// ---------------------------------------------------------------------------
// K3: bf16 transpose per batch: xb[b][j][d] -> xbT[b][d][j], 64x64 tiles.
// ---------------------------------------------------------------------------
__global__ __launch_bounds__(256) void transpose_kernel(const unsigned short* __restrict__ in,
        unsigned short* __restrict__ out) {
    int b  = blockIdx.z;
    int j0 = blockIdx.y * 64;
    int d0 = blockIdx.x * 64;
    __shared__ unsigned short tile[64][66];
    const unsigned short* ip = in + ((size_t)b * N_ + j0) * D_ + d0;
    int t = threadIdx.x;
    #pragma unroll
    for (int c = t; c < 512; c += 256) {
        int r = c >> 3, col = (c & 7) * 8;
        uint4 val = *(const uint4*)(ip + (size_t)r * D_ + col);
        unsigned int* dst = (unsigned int*)&tile[r][col];
        dst[0] = val.x; dst[1] = val.y; dst[2] = val.z; dst[3] = val.w;
    }
    __syncthreads();
    unsigned short* op = out + ((size_t)b * D_ + d0) * N_ + j0;
    #pragma unroll
    for (int c = t; c < 512; c += 256) {
        int r = c >> 3, col = (c & 7) * 8;
        unsigned short vals[8];
        #pragma unroll
        for (int k = 0; k < 8; k++) vals[k] = tile[col + k][r];
        uint4 o;
        o.x = (unsigned)vals[0] | ((unsigned)vals[1] << 16);
        o.y = (unsigned)vals[2] | ((unsigned)vals[3] << 16);
        o.z = (unsigned)vals[4] | ((unsigned)vals[5] << 16);
        o.w = (unsigned)vals[6] | ((unsigned)vals[7] << 16);
        *(uint4*)(op + (size_t)r * N_ + col) = o;
    }
}

extern "C" void kernel_launch(void* const* d_in, const int* in_sizes, int n_in,
                              void* d_out, int out_size, void* d_ws, size_t ws_size,
                              hipStream_t stream) {
    const float* x = (const float*)d_in[0];
    float* out = (float*)d_out;
    char* ws = (char*)d_ws;

    // layout: [pb 64M][xb 64M][xbT 64M][attnE 64M][lse 128K][rowsum 128K]
    unsigned short* pb    = (unsigned short*)(ws);
    unsigned short* xb    = (unsigned short*)(ws + 67108864ULL);
    unsigned short* xbT   = (unsigned short*)(ws + 134217728ULL);
    unsigned short* attnE = (unsigned short*)(ws + 201326592ULL);
    float*          lse   = (float*)(ws + 268435456ULL);
    float*          rowsum= (float*)(ws + 268566528ULL);

    prep_kernel<<<dim3(B_ * N_ / 4), 256, 0, stream>>>(x, pb, xb, lse, rowsum);
    transpose_kernel<<<dim3(16, 16, B_), 256, 0, stream>>>(xb, xbT);
    gemm_bt<0><<<dim3(8, 4, B_), 512, 73728, stream>>>(pb, xb, attnE, lse, rowsum);
    gemm_bt<1><<<dim3(8, 4, B_), 512, 73728, stream>>>(attnE, xbT, out, nullptr, rowsum);
}